// Round 8
// baseline (107.285 us; speedup 1.0000x reference)
//
#include <hip/hip_runtime.h>
#include <math.h>

#define C_INK   1024
#define C1D     256
#define C2D     128
#define OUTD    2048
#define R_ROI   512
#define MPIX    32768

#define NSIDE   128            // cvt side-blocks prepended to conv grid

typedef _Float16 half8 __attribute__((ext_vector_type(8)));
typedef float    f32x4 __attribute__((ext_vector_type(4)));

__device__ __forceinline__ unsigned int pack2h(float a, float b) {
    union { _Float16 h[2]; unsigned int u; } p;
    p.h[0] = (_Float16)a; p.h[1] = (_Float16)b;
    return p.u;
}
__device__ __forceinline__ float eluf(float v) { return v > 0.f ? v : expf(v) - 1.f; }

// XOR-swizzled LDS accessor: logical [row][chunk], chunk = 16B (8 halves),
// RC = chunks per row. slot = ch ^ (row&7).
template<int RC>
__device__ __forceinline__ half8* ldsq(_Float16* base, int row, int ch) {
    return reinterpret_cast<half8*>(base) + row * RC + (ch ^ (row & 7));
}

// ---------------------------------------------------------------------------
// Kernel 0: w1 fp32 -> fp16
// ---------------------------------------------------------------------------
__global__ __launch_bounds__(256) void cvt_w1(
    const float* __restrict__ w1, _Float16* __restrict__ w1h)
{
    const int i0 = (blockIdx.x * 256 + threadIdx.x) * 4;
    #pragma unroll
    for (int j = 0; j < 4; ++j) {
        const int i = (i0 + j) * 4;
        const float4 v = *reinterpret_cast<const float4*>(w1 + i);
        uint2 u; u.x = pack2h(v.x, v.y); u.y = pack2h(v.z, v.w);
        *reinterpret_cast<uint2*>(w1h + i) = u;
    }
}

// ---------------------------------------------------------------------------
// Kernel 1: conv1x1 (+ side-block conversion of w2,wl).
// z[pix][oc] = sum_k x[b][k][pix] * w1[oc][k]
// BM=32 pixels, BN=256, BK=64. 1024 blocks x 512 thr, VGPR<=64 (launch_bounds
// (512,8)) -> 4 blocks/CU, 32 waves/CU. Wave = 32px x 32oc (mi=2,ni=2).
// A: LDS double-buffered 2x4KB, 1 barrier/tile, reg-prefetch 1 tile ahead.
// B: 4 x half8 from L2-resident w1h per tile, single-buffered (TLP covers).
// ---------------------------------------------------------------------------
__global__ __launch_bounds__(512, 8) void conv1x1_f16(
    const float* __restrict__ x, const _Float16* __restrict__ w1h,
    const float* __restrict__ w2, const float* __restrict__ wl,
    _Float16* __restrict__ w2h, _Float16* __restrict__ wlh,
    _Float16* __restrict__ z)
{
    const int bid = blockIdx.x;
    const int tid = threadIdx.x;

    if (bid < NSIDE) {
        // side job: convert w2 (8192 float4) then wl (1048576 float4)
        constexpr int NF4_W2 = (C2D * C1D) / 4;
        constexpr int NF4    = NF4_W2 + (OUTD * OUTD) / 4;
        for (int i = bid * 512 + tid; i < NF4; i += NSIDE * 512) {
            const float* s; _Float16* d; int e;
            if (i < NF4_W2) { s = w2; d = w2h; e = i * 4; }
            else            { s = wl; d = wlh; e = (i - NF4_W2) * 4; }
            const float4 v = *reinterpret_cast<const float4*>(s + e);
            uint2 u; u.x = pack2h(v.x, v.y); u.y = pack2h(v.z, v.w);
            *reinterpret_cast<uint2*>(d + e) = u;
        }
        return;
    }

    __shared__ __align__(16) _Float16 As[2][32 * 64];   // 2 x 4 KB

    const int lane = tid & 63;
    const int wave = tid >> 6;          // 0..7: oc-group AND staging k-octet
    const int m0   = (bid - NSIDE) * 32;
    const int b    = m0 >> 12;
    const int p0   = m0 & 4095;
    const int px   = lane & 31;         // staging pixel
    const int krow = lane >> 5;         // staging k-quad select (0/1)

    const float* xbase = x + (size_t)b * C_INK * 4096 + p0 + px;
    // B fragments: oc row = wave*32 + ni*16 + (lane&15), k-octet = lane>>4
    const _Float16* wbase = w1h + (size_t)(wave * 32 + (lane & 15)) * C_INK + (lane >> 4) * 8;

    float ar_a[4], ar_b[4];
    f32x4 acc[2][2];
    #pragma unroll
    for (int i = 0; i < 2; ++i)
        #pragma unroll
        for (int j = 0; j < 2; ++j) acc[i][j] = (f32x4){0.f, 0.f, 0.f, 0.f};

    auto LOADA = [&](float (&ar)[4], int t) {
        // lane covers k = t*64 + wave*8 + krow*4 + j  (4 consecutive k)
        const float* xk = xbase + (size_t)(t * 64 + wave * 8 + krow * 4) * 4096;
        #pragma unroll
        for (int j = 0; j < 4; ++j) ar[j] = xk[(size_t)j * 4096];
    };
    auto WRITEA = [&](int buf, float (&ar)[4]) {
        uint2 u; u.x = pack2h(ar[0], ar[1]); u.y = pack2h(ar[2], ar[3]);
        // chunk index = wave (k-octet), half = krow; swizzle chunk by px&7
        char* p = (char*)&As[buf][0] + px * 128 + ((wave ^ (px & 7)) << 4) + krow * 8;
        *reinterpret_cast<uint2*>(p) = u;
    };
    auto COMPUTE = [&](int buf, int t) {
        half8 bf[2][2];
        #pragma unroll
        for (int kk = 0; kk < 2; ++kk)
            #pragma unroll
            for (int ni = 0; ni < 2; ++ni)
                bf[kk][ni] = *reinterpret_cast<const half8*>(
                    wbase + (size_t)ni * 16 * C_INK + t * 64 + kk * 32);
        #pragma unroll
        for (int kk = 0; kk < 2; ++kk) {
            const int ch = kk * 4 + (lane >> 4);
            half8 af[2];
            #pragma unroll
            for (int mi = 0; mi < 2; ++mi)
                af[mi] = *ldsq<8>(&As[buf][0], mi * 16 + (lane & 15), ch);
            #pragma unroll
            for (int mi = 0; mi < 2; ++mi)
                #pragma unroll
                for (int ni = 0; ni < 2; ++ni)   // swapped: quad side = oc
                    acc[mi][ni] = __builtin_amdgcn_mfma_f32_16x16x32_f16(bf[kk][ni], af[mi], acc[mi][ni], 0, 0, 0);
        }
    };

    // prologue: tile0 staged, tile1 in regs
    LOADA(ar_a, 0); WRITEA(0, ar_a);
    LOADA(ar_b, 1);
    __syncthreads();

    #pragma unroll
    for (int tp = 0; tp < 8; ++tp) {
        const int t = 2 * tp;
        // even: compute t (buf0); stage t+1 into buf1; load t+2
        WRITEA(1, ar_b);
        if (tp < 7) LOADA(ar_a, t + 2);
        COMPUTE(0, t);
        __syncthreads();
        // odd: compute t+1 (buf1); stage t+2 into buf0; load t+3
        if (tp < 7) { WRITEA(0, ar_a); LOADA(ar_b, t + 3); }
        COMPUTE(1, t + 1);
        __syncthreads();
    }

    _Float16* zp = z + (size_t)m0 * C1D;
    #pragma unroll
    for (int mi = 0; mi < 2; ++mi) {
        const int pixel = mi * 16 + (lane & 15);
        #pragma unroll
        for (int ni = 0; ni < 2; ++ni) {
            const int oc0 = wave * 32 + ni * 16 + (lane >> 4) * 4;
            uint2 u;
            u.x = pack2h(acc[mi][ni][0], acc[mi][ni][1]);
            u.y = pack2h(acc[mi][ni][2], acc[mi][ni][3]);
            *reinterpret_cast<uint2*>(&zp[(size_t)pixel * C1D + oc0]) = u;
        }
    }
}

// ---------------------------------------------------------------------------
// Kernel 2: fused ROI-align gather + bias/ELU + gemm2 + bias/ELU -> h2 row.
// 512 threads, one block per ROI. w2 B-frags in registers (prefetched at
// kernel top). LDS = 16x256 H1 tile only. XCD-swizzled block->ROI map.
// ---------------------------------------------------------------------------
__global__ __launch_bounds__(512) void roi_gemm2_f16(
    const _Float16* __restrict__ z, const float* __restrict__ boxes,
    const float* __restrict__ scale_p, const float* __restrict__ b1v,
    const _Float16* __restrict__ w2h, const float* __restrict__ b2v,
    _Float16* __restrict__ h2)
{
    __shared__ __align__(16) _Float16 H1s[16 * 256];   // 8 KB, swizzled RC=32
    __shared__ int   s_off[64][4];
    __shared__ float s_w[64][4];

    const int bid  = blockIdx.x;
    const int r    = (bid & 7) * 64 + (bid >> 3);      // image i -> XCD i
    const int tid  = threadIdx.x;
    const int lane = tid & 63;
    const int wv   = tid >> 6;          // 0..7 -> output cols wv*16..wv*16+15

    // prefetch w2 B-fragments into registers (independent of gather)
    half8 bfr[8];
    {
        const _Float16* wp = w2h + (size_t)(wv * 16 + (lane & 15)) * C1D + (lane >> 4) * 8;
        #pragma unroll
        for (int ks = 0; ks < 8; ++ks)
            bfr[ks] = *reinterpret_cast<const half8*>(wp + ks * 32);
    }

    if (tid < 64) {
        const float sc = scale_p[0];
        const float x1 = boxes[r * 4 + 0] * sc, y1 = boxes[r * 4 + 1] * sc;
        const float x2 = boxes[r * 4 + 2] * sc, y2 = boxes[r * 4 + 3] * sc;
        const float rw = fmaxf(x2 - x1, 1.f), rh = fmaxf(y2 - y1, 1.f);
        const int jy = tid >> 3, jx = tid & 7;

        float offy = (float)(jy >> 1) + (float)(jy & 1) * 0.5f + 0.25f;
        float cy = y1 + offy * rh * 0.25f;
        const bool vy = (cy >= -1.f) && (cy <= 64.f);
        cy = fminf(fmaxf(cy, 0.f), 63.f);
        int ylo = (int)cy; if (ylo > 63) ylo = 63;
        int yhi = ylo + 1; if (yhi > 63) yhi = 63;
        const float ly = cy - (float)ylo, hy = 1.f - ly;

        float offx = (float)(jx >> 1) + (float)(jx & 1) * 0.5f + 0.25f;
        float cx = x1 + offx * rw * 0.25f;
        const bool vx = (cx >= -1.f) && (cx <= 64.f);
        cx = fminf(fmaxf(cx, 0.f), 63.f);
        int xlo = (int)cx; if (xlo > 63) xlo = 63;
        int xhi = xlo + 1; if (xhi > 63) xhi = 63;
        const float lx = cx - (float)xlo, hx = 1.f - lx;

        const float wm = (vy && vx) ? 0.25f : 0.f;     // fold 2x2 mean
        s_w[tid][0] = hy * hx * wm;
        s_w[tid][1] = hy * lx * wm;
        s_w[tid][2] = ly * hx * wm;
        s_w[tid][3] = ly * lx * wm;
        s_off[tid][0] = (ylo * 64 + xlo) * C1D;
        s_off[tid][1] = (ylo * 64 + xhi) * C1D;
        s_off[tid][2] = (yhi * 64 + xlo) * C1D;
        s_off[tid][3] = (yhi * 64 + xhi) * C1D;
    }
    __syncthreads();

    // gather: thread = (channel-octet ch8 = tid&31, cell = tid>>5)
    {
        const int ch8  = tid & 31;
        const int cell = tid >> 5;
        const _Float16* zb = z + (size_t)(r >> 6) * 4096 * C1D + ch8 * 8;

        float accv[8];
        #pragma unroll
        for (int e = 0; e < 8; ++e) accv[e] = 0.f;

        const int py = cell >> 2, px = cell & 3;
        #pragma unroll
        for (int u = 0; u < 4; ++u) {
            const int s = (py * 2 + (u >> 1)) * 8 + px * 2 + (u & 1);
            #pragma unroll
            for (int k = 0; k < 4; ++k) {
                const half8 v = *reinterpret_cast<const half8*>(zb + s_off[s][k]);
                const float w = s_w[s][k];
                #pragma unroll
                for (int e = 0; e < 8; ++e) accv[e] += (float)v[e] * w;
            }
        }

        const float4 b0 = *reinterpret_cast<const float4*>(&b1v[ch8 * 8]);
        const float4 b4 = *reinterpret_cast<const float4*>(&b1v[ch8 * 8 + 4]);
        half8 o;
        o[0] = (_Float16)eluf(accv[0] + b0.x); o[1] = (_Float16)eluf(accv[1] + b0.y);
        o[2] = (_Float16)eluf(accv[2] + b0.z); o[3] = (_Float16)eluf(accv[3] + b0.w);
        o[4] = (_Float16)eluf(accv[4] + b4.x); o[5] = (_Float16)eluf(accv[5] + b4.y);
        o[6] = (_Float16)eluf(accv[6] + b4.z); o[7] = (_Float16)eluf(accv[7] + b4.w);
        *ldsq<32>(H1s, cell, ch8) = o;
    }
    __syncthreads();

    // MFMA: wave wv computes C[16 cells x 16 cols], K=256
    f32x4 oa = (f32x4){0.f, 0.f, 0.f, 0.f};
    #pragma unroll
    for (int ks = 0; ks < 8; ++ks) {
        const int ch = ks * 4 + (lane >> 4);
        const half8 af = *ldsq<32>(H1s, lane & 15, ch);
        oa = __builtin_amdgcn_mfma_f32_16x16x32_f16(af, bfr[ks], oa, 0, 0, 0);
    }

    // epilogue
    {
        const int o  = wv * 16 + (lane & 15);
        const int p0 = (lane >> 4) * 4;
        const float bv = b2v[o];
        uint2 u;
        u.x = pack2h(eluf(oa[0] + bv), eluf(oa[1] + bv));
        u.y = pack2h(eluf(oa[2] + bv), eluf(oa[3] + bv));
        *reinterpret_cast<uint2*>(&h2[(size_t)r * 2048 + o * 16 + p0]) = u;
    }
}

// ---------------------------------------------------------------------------
// Kernel 3: NT GEMM out = elu(h2 @ wl^T + bl), fp32 out.
// BM=64, BN=64, BK=128, 512 threads (8 waves 2x4, wave = 32m x 16n).
// Grid 256 flat: n-slice = bid&31 -> m-blocks of a wl slice share an XCD.
// ---------------------------------------------------------------------------
__global__ __launch_bounds__(512) void gemm_nt_out(
    const _Float16* __restrict__ A, const _Float16* __restrict__ W,
    const float* __restrict__ bias, float* __restrict__ Cout)
{
    constexpr int K = OUTD, N = OUTD;
    __shared__ __align__(16) _Float16 As[64 * 128];    // 16 KB
    __shared__ __align__(16) _Float16 Bs[64 * 128];    // 16 KB

    const int bid  = blockIdx.x;                 // 0..255
    const int m0   = (bid >> 5) * 64;
    const int n0   = (bid & 31) * 64;

    const int tid  = threadIdx.x;
    const int lane = tid & 63;
    const int wave = tid >> 6;
    const int wr   = wave >> 2, wc = wave & 3;   // wave = 32m x 16n
    const int c    = tid & 7;                    // chunk pair base
    const int r0   = tid >> 3;                   // 0..63

    half8 arg[2], brg[2];
    f32x4 acc[2];
    acc[0] = (f32x4){0.f, 0.f, 0.f, 0.f};
    acc[1] = (f32x4){0.f, 0.f, 0.f, 0.f};

    auto LOADT = [&](int k0) {
        const _Float16* ap = &A[(size_t)(m0 + r0) * K + k0 + c * 16];
        arg[0] = *reinterpret_cast<const half8*>(ap);
        arg[1] = *reinterpret_cast<const half8*>(ap + 8);
        const _Float16* wp = &W[(size_t)(n0 + r0) * K + k0 + c * 16];
        brg[0] = *reinterpret_cast<const half8*>(wp);
        brg[1] = *reinterpret_cast<const half8*>(wp + 8);
    };
    auto WRITET = [&]() {
        *ldsq<16>(As, r0, 2 * c)     = arg[0];
        *ldsq<16>(As, r0, 2 * c + 1) = arg[1];
        *ldsq<16>(Bs, r0, 2 * c)     = brg[0];
        *ldsq<16>(Bs, r0, 2 * c + 1) = brg[1];
    };
    auto COMPUTET = [&]() {
        #pragma unroll
        for (int kk = 0; kk < 4; ++kk) {
            const int ch = kk * 4 + (lane >> 4);
            half8 af[2], bf;
            af[0] = *ldsq<16>(As, wr * 32 + (lane & 15), ch);
            af[1] = *ldsq<16>(As, wr * 32 + 16 + (lane & 15), ch);
            bf    = *ldsq<16>(Bs, wc * 16 + (lane & 15), ch);
            acc[0] = __builtin_amdgcn_mfma_f32_16x16x32_f16(bf, af[0], acc[0], 0, 0, 0);
            acc[1] = __builtin_amdgcn_mfma_f32_16x16x32_f16(bf, af[1], acc[1], 0, 0, 0);
        }
    };

    constexpr int nt = K / 128;    // 16
    LOADT(0); WRITET(); __syncthreads();
    for (int t = 0; t < nt - 1; ++t) {
        LOADT((t + 1) * 128);
        COMPUTET();
        __syncthreads();
        WRITET();
        __syncthreads();
    }
    COMPUTET();

    #pragma unroll
    for (int mi = 0; mi < 2; ++mi) {
        const int row  = m0 + wr * 32 + mi * 16 + (lane & 15);
        const int col0 = n0 + wc * 16 + (lane >> 4) * 4;
        const float4 bv = *reinterpret_cast<const float4*>(&bias[col0]);
        float4 o;
        o.x = eluf(acc[mi][0] + bv.x);
        o.y = eluf(acc[mi][1] + bv.y);
        o.z = eluf(acc[mi][2] + bv.z);
        o.w = eluf(acc[mi][3] + bv.w);
        *reinterpret_cast<float4*>(&Cout[(size_t)row * N + col0]) = o;
    }
}

// ---------------------------------------------------------------------------
extern "C" void kernel_launch(void* const* d_in, const int* in_sizes, int n_in,
                              void* d_out, int out_size, void* d_ws, size_t ws_size,
                              hipStream_t stream) {
    const float* x     = (const float*)d_in[0];
    const float* boxes = (const float*)d_in[1];
    const float* scale = (const float*)d_in[2];
    const float* w1    = (const float*)d_in[3];
    const float* b1    = (const float*)d_in[4];
    const float* w2    = (const float*)d_in[5];
    const float* b2    = (const float*)d_in[6];
    const float* wl    = (const float*)d_in[7];
    const float* bl    = (const float*)d_in[8];
    float* out = (float*)d_out;

    // workspace layout (fp16 halves)
    _Float16* z   = (_Float16*)d_ws;                    // 32768 x 256
    _Float16* h2  = z   + (size_t)MPIX * C1D;           //   512 x 2048
    _Float16* w1h = h2  + (size_t)R_ROI * OUTD;         //   256 x 1024
    _Float16* w2h = w1h + (size_t)C1D * C_INK;          //   128 x 256
    _Float16* wlh = w2h + (size_t)C2D * C1D;            //  2048 x 2048

    // 0) w1 -> fp16 (conv reads w1h from its first tile)
    cvt_w1<<<dim3(64), dim3(256), 0, stream>>>(w1, w1h);

    // 1) z = x @ w1^T (channels-last fp16); side-blocks convert w2/wl
    conv1x1_f16<<<dim3(NSIDE + MPIX / 32), dim3(512), 0, stream>>>(
        x, w1h, w2, wl, w2h, wlh, z);

    // 2) h2 = elu( elu(roi_align(z)+b1) @ w2^T + b2 )  -- fused, one block/ROI
    roi_gemm2_f16<<<dim3(R_ROI), dim3(512), 0, stream>>>(
        z, boxes, scale, b1, w2h, b2, h2);

    // 3) out = elu(h2 @ wl^T + bl)
    gemm_nt_out<<<dim3(256), dim3(512), 0, stream>>>(h2, wlh, bl, out);
}

// Round 9
// 77.461 us; speedup vs baseline: 1.3850x; 1.3850x over previous
//
#include <hip/hip_runtime.h>
#include <math.h>

#define C_INK   1024
#define C1D     256
#define C2D     128
#define OUTD    2048
#define R_ROI   512
#define MPIX    32768

#define NSIDE   128            // cvt side-blocks prepended to conv grid

typedef _Float16 half8 __attribute__((ext_vector_type(8)));
typedef float    f32x4 __attribute__((ext_vector_type(4)));

__device__ __forceinline__ unsigned int pack2h(float a, float b) {
    union { _Float16 h[2]; unsigned int u; } p;
    p.h[0] = (_Float16)a; p.h[1] = (_Float16)b;
    return p.u;
}
__device__ __forceinline__ float eluf(float v) { return v > 0.f ? v : expf(v) - 1.f; }

// XOR-swizzled LDS accessor: logical [row][chunk], chunk = 16B (8 halves),
// RC = chunks per row. slot = ch ^ (row&7).
template<int RC>
__device__ __forceinline__ half8* ldsq(_Float16* base, int row, int ch) {
    return reinterpret_cast<half8*>(base) + row * RC + (ch ^ (row & 7));
}

// ---------------------------------------------------------------------------
// Kernel 0: w1 fp32 -> fp16 (w1h needed by conv's B-path at kernel start)
// ---------------------------------------------------------------------------
__global__ __launch_bounds__(256) void cvt_w1(
    const float* __restrict__ w1, _Float16* __restrict__ w1h)
{
    const int i0 = (blockIdx.x * 256 + threadIdx.x) * 4;
    #pragma unroll
    for (int j = 0; j < 4; ++j) {
        const int i = (i0 + j) * 4;
        const float4 v = *reinterpret_cast<const float4*>(w1 + i);
        uint2 u; u.x = pack2h(v.x, v.y); u.y = pack2h(v.z, v.w);
        *reinterpret_cast<uint2*>(w1h + i) = u;
    }
}

// ---------------------------------------------------------------------------
// Kernel 1: conv1x1 (+ side-block conversion of w2,wl).
// z[pix][oc] = sum_k x[b][k][pix] * w1[oc][k]
// BM=64 pixels, BN=256 (full C1 -> x read once), BK=64, 512 thr = 8 waves.
// LDS: A only, double-buffered (16 KB). B (w1h fp16) straight to registers
// from L2. 2-deep prefetch, loop unrolled x2 with static reg sets.
// ---------------------------------------------------------------------------
__global__ __launch_bounds__(512, 4) void conv1x1_f16(
    const float* __restrict__ x, const _Float16* __restrict__ w1h,
    const float* __restrict__ w2, const float* __restrict__ wl,
    _Float16* __restrict__ w2h, _Float16* __restrict__ wlh,
    _Float16* __restrict__ z)
{
    const int bid = blockIdx.x;
    const int tid = threadIdx.x;

    if (bid < NSIDE) {
        // side job: convert w2 (8192 float4) then wl (1048576 float4)
        constexpr int NF4_W2 = (C2D * C1D) / 4;
        constexpr int NF4    = NF4_W2 + (OUTD * OUTD) / 4;
        for (int i = bid * 512 + tid; i < NF4; i += NSIDE * 512) {
            const float* s; _Float16* d; int e;
            if (i < NF4_W2) { s = w2; d = w2h; e = i * 4; }
            else            { s = wl; d = wlh; e = (i - NF4_W2) * 4; }
            const float4 v = *reinterpret_cast<const float4*>(s + e);
            uint2 u; u.x = pack2h(v.x, v.y); u.y = pack2h(v.z, v.w);
            *reinterpret_cast<uint2*>(d + e) = u;
        }
        return;
    }

    __shared__ __align__(16) _Float16 As[2][64 * 64];   // 2 x 8 KB

    const int lane = tid & 63;
    const int wave = tid >> 6;          // 0..7
    const int m0   = (bid - NSIDE) * 64;
    const int b    = m0 >> 12;
    const int p0   = m0 & 4095;

    const float* xbase = x + (size_t)b * C_INK * 4096 + p0 + lane;
    // B fragment base: wave's oc rows, lane's k-octet
    const _Float16* wbase = w1h + (size_t)(wave * 32 + (lane & 15)) * C_INK + (lane >> 4) * 8;

    float ar_a[8], ar_b[8];
    half8 bf_a[2][2], bf_b[2][2];
    f32x4 acc[4][2];
    #pragma unroll
    for (int i = 0; i < 4; ++i)
        #pragma unroll
        for (int j = 0; j < 2; ++j) acc[i][j] = (f32x4){0.f, 0.f, 0.f, 0.f};

    auto LOADA = [&](float (&ar)[8], int k0) {
        const float* xk = xbase + (size_t)(k0 + wave * 8) * 4096;
        #pragma unroll
        for (int j = 0; j < 8; ++j) ar[j] = xk[(size_t)j * 4096];
    };
    auto LOADB = [&](half8 (&bf)[2][2], int k0) {
        #pragma unroll
        for (int kk = 0; kk < 2; ++kk)
            #pragma unroll
            for (int ni = 0; ni < 2; ++ni)
                bf[kk][ni] = *reinterpret_cast<const half8*>(
                    wbase + (size_t)ni * 16 * C_INK + k0 + kk * 32);
    };
    auto WRITEA = [&](int buf, float (&ar)[8]) {
        union { half8 h; unsigned int u[4]; } pk;
        #pragma unroll
        for (int j = 0; j < 4; ++j) pk.u[j] = pack2h(ar[2 * j], ar[2 * j + 1]);
        *ldsq<8>(&As[buf][0], lane, wave) = pk.h;   // row = pixel, chunk = k-octet
    };
    auto COMPUTE = [&](int buf, half8 (&bf)[2][2]) {
        #pragma unroll
        for (int kk = 0; kk < 2; ++kk) {
            const int ch = kk * 4 + (lane >> 4);
            half8 af[4];
            #pragma unroll
            for (int mi = 0; mi < 4; ++mi)
                af[mi] = *ldsq<8>(&As[buf][0], mi * 16 + (lane & 15), ch);
            #pragma unroll
            for (int mi = 0; mi < 4; ++mi)
                #pragma unroll
                for (int ni = 0; ni < 2; ++ni)   // swapped: quad side = oc
                    acc[mi][ni] = __builtin_amdgcn_mfma_f32_16x16x32_f16(bf[kk][ni], af[mi], acc[mi][ni], 0, 0, 0);
        }
    };

    // prologue: tiles 0 and 1 in flight
    LOADA(ar_a, 0);   LOADB(bf_a, 0);
    LOADA(ar_b, 64);  LOADB(bf_b, 64);
    WRITEA(0, ar_a);
    __syncthreads();

    // steady state: 8 double-iterations (16 K-tiles)
    #pragma unroll
    for (int tp = 0; tp < 8; ++tp) {
        const int t = 2 * tp;
        // ---- even tile t ----
        if (tp < 7) LOADA(ar_a, (t + 2) * 64);   // issue early: used next iter
        WRITEA(1, ar_b);                         // waits only ar_b (prev iter)
        COMPUTE(0, bf_a);
        if (tp < 7) LOADB(bf_a, (t + 2) * 64);
        __syncthreads();
        // ---- odd tile t+1 ----
        if (tp < 7) {
            LOADA(ar_b, (t + 3) * 64);
            WRITEA(0, ar_a);
        }
        COMPUTE(1, bf_b);
        if (tp < 7) LOADB(bf_b, (t + 3) * 64);
        __syncthreads();
    }

    _Float16* zp = z + (size_t)m0 * C1D;
    #pragma unroll
    for (int mi = 0; mi < 4; ++mi) {
        const int pixel = mi * 16 + (lane & 15);
        #pragma unroll
        for (int ni = 0; ni < 2; ++ni) {
            const int oc0 = wave * 32 + ni * 16 + (lane >> 4) * 4;
            uint2 u;
            u.x = pack2h(acc[mi][ni][0], acc[mi][ni][1]);
            u.y = pack2h(acc[mi][ni][2], acc[mi][ni][3]);
            *reinterpret_cast<uint2*>(&zp[(size_t)pixel * C1D + oc0]) = u;
        }
    }
}

// ---------------------------------------------------------------------------
// Kernel 2: fused ROI-align gather + bias/ELU + gemm2 + bias/ELU -> h2 row.
// 512 threads, one block per ROI. w2 B-frags in registers (prefetched at
// kernel top). LDS = 16x256 H1 tile only. XCD-swizzled block->ROI map.
// ---------------------------------------------------------------------------
__global__ __launch_bounds__(512) void roi_gemm2_f16(
    const _Float16* __restrict__ z, const float* __restrict__ boxes,
    const float* __restrict__ scale_p, const float* __restrict__ b1v,
    const _Float16* __restrict__ w2h, const float* __restrict__ b2v,
    _Float16* __restrict__ h2)
{
    __shared__ __align__(16) _Float16 H1s[16 * 256];   // 8 KB, swizzled RC=32
    __shared__ int   s_off[64][4];
    __shared__ float s_w[64][4];

    const int bid  = blockIdx.x;
    const int r    = (bid & 7) * 64 + (bid >> 3);      // image i -> XCD i
    const int tid  = threadIdx.x;
    const int lane = tid & 63;
    const int wv   = tid >> 6;          // 0..7 -> output cols wv*16..wv*16+15

    // prefetch w2 B-fragments into registers (independent of gather)
    half8 bfr[8];
    {
        const _Float16* wp = w2h + (size_t)(wv * 16 + (lane & 15)) * C1D + (lane >> 4) * 8;
        #pragma unroll
        for (int ks = 0; ks < 8; ++ks)
            bfr[ks] = *reinterpret_cast<const half8*>(wp + ks * 32);
    }

    if (tid < 64) {
        const float sc = scale_p[0];
        const float x1 = boxes[r * 4 + 0] * sc, y1 = boxes[r * 4 + 1] * sc;
        const float x2 = boxes[r * 4 + 2] * sc, y2 = boxes[r * 4 + 3] * sc;
        const float rw = fmaxf(x2 - x1, 1.f), rh = fmaxf(y2 - y1, 1.f);
        const int jy = tid >> 3, jx = tid & 7;

        float offy = (float)(jy >> 1) + (float)(jy & 1) * 0.5f + 0.25f;
        float cy = y1 + offy * rh * 0.25f;
        const bool vy = (cy >= -1.f) && (cy <= 64.f);
        cy = fminf(fmaxf(cy, 0.f), 63.f);
        int ylo = (int)cy; if (ylo > 63) ylo = 63;
        int yhi = ylo + 1; if (yhi > 63) yhi = 63;
        const float ly = cy - (float)ylo, hy = 1.f - ly;

        float offx = (float)(jx >> 1) + (float)(jx & 1) * 0.5f + 0.25f;
        float cx = x1 + offx * rw * 0.25f;
        const bool vx = (cx >= -1.f) && (cx <= 64.f);
        cx = fminf(fmaxf(cx, 0.f), 63.f);
        int xlo = (int)cx; if (xlo > 63) xlo = 63;
        int xhi = xlo + 1; if (xhi > 63) xhi = 63;
        const float lx = cx - (float)xlo, hx = 1.f - lx;

        const float wm = (vy && vx) ? 0.25f : 0.f;     // fold 2x2 mean
        s_w[tid][0] = hy * hx * wm;
        s_w[tid][1] = hy * lx * wm;
        s_w[tid][2] = ly * hx * wm;
        s_w[tid][3] = ly * lx * wm;
        s_off[tid][0] = (ylo * 64 + xlo) * C1D;
        s_off[tid][1] = (ylo * 64 + xhi) * C1D;
        s_off[tid][2] = (yhi * 64 + xlo) * C1D;
        s_off[tid][3] = (yhi * 64 + xhi) * C1D;
    }
    __syncthreads();

    // gather: thread = (channel-octet ch8 = tid&31, cell = tid>>5)
    {
        const int ch8  = tid & 31;
        const int cell = tid >> 5;
        const _Float16* zb = z + (size_t)(r >> 6) * 4096 * C1D + ch8 * 8;

        float accv[8];
        #pragma unroll
        for (int e = 0; e < 8; ++e) accv[e] = 0.f;

        const int py = cell >> 2, px = cell & 3;
        #pragma unroll
        for (int u = 0; u < 4; ++u) {
            const int s = (py * 2 + (u >> 1)) * 8 + px * 2 + (u & 1);
            #pragma unroll
            for (int k = 0; k < 4; ++k) {
                const half8 v = *reinterpret_cast<const half8*>(zb + s_off[s][k]);
                const float w = s_w[s][k];
                #pragma unroll
                for (int e = 0; e < 8; ++e) accv[e] += (float)v[e] * w;
            }
        }

        const float4 b0 = *reinterpret_cast<const float4*>(&b1v[ch8 * 8]);
        const float4 b4 = *reinterpret_cast<const float4*>(&b1v[ch8 * 8 + 4]);
        half8 o;
        o[0] = (_Float16)eluf(accv[0] + b0.x); o[1] = (_Float16)eluf(accv[1] + b0.y);
        o[2] = (_Float16)eluf(accv[2] + b0.z); o[3] = (_Float16)eluf(accv[3] + b0.w);
        o[4] = (_Float16)eluf(accv[4] + b4.x); o[5] = (_Float16)eluf(accv[5] + b4.y);
        o[6] = (_Float16)eluf(accv[6] + b4.z); o[7] = (_Float16)eluf(accv[7] + b4.w);
        *ldsq<32>(H1s, cell, ch8) = o;
    }
    __syncthreads();

    // MFMA: wave wv computes C[16 cells x 16 cols], K=256
    f32x4 oa = (f32x4){0.f, 0.f, 0.f, 0.f};
    #pragma unroll
    for (int ks = 0; ks < 8; ++ks) {
        const int ch = ks * 4 + (lane >> 4);
        const half8 af = *ldsq<32>(H1s, lane & 15, ch);
        oa = __builtin_amdgcn_mfma_f32_16x16x32_f16(af, bfr[ks], oa, 0, 0, 0);
    }

    // epilogue: D cell = (lane>>4)*4+j (consecutive), col o = lane&15
    {
        const int o  = wv * 16 + (lane & 15);
        const int p0 = (lane >> 4) * 4;
        const float bv = b2v[o];
        uint2 u;
        u.x = pack2h(eluf(oa[0] + bv), eluf(oa[1] + bv));
        u.y = pack2h(eluf(oa[2] + bv), eluf(oa[3] + bv));
        *reinterpret_cast<uint2*>(&h2[(size_t)r * 2048 + o * 16 + p0]) = u;
    }
}

// ---------------------------------------------------------------------------
// Kernel 3: NT GEMM out = elu(h2 @ wl^T + bl), fp32 out.
// BM=64, BN=64, BK=128, 512 threads (8 waves 2x4, wave = 32m x 16n).
// Grid 256 flat: n-slice = bid&31 -> m-blocks of a wl slice share an XCD.
// ---------------------------------------------------------------------------
__global__ __launch_bounds__(512) void gemm_nt_out(
    const _Float16* __restrict__ A, const _Float16* __restrict__ W,
    const float* __restrict__ bias, float* __restrict__ Cout)
{
    constexpr int K = OUTD, N = OUTD;
    __shared__ __align__(16) _Float16 As[64 * 128];    // 16 KB
    __shared__ __align__(16) _Float16 Bs[64 * 128];    // 16 KB

    const int bid  = blockIdx.x;                 // 0..255
    const int m0   = (bid >> 5) * 64;
    const int n0   = (bid & 31) * 64;

    const int tid  = threadIdx.x;
    const int lane = tid & 63;
    const int wave = tid >> 6;
    const int wr   = wave >> 2, wc = wave & 3;   // wave = 32m x 16n
    const int c    = tid & 7;                    // chunk pair base
    const int r0   = tid >> 3;                   // 0..63

    half8 arg[2], brg[2];
    f32x4 acc[2];
    acc[0] = (f32x4){0.f, 0.f, 0.f, 0.f};
    acc[1] = (f32x4){0.f, 0.f, 0.f, 0.f};

    auto LOADT = [&](int k0) {
        const _Float16* ap = &A[(size_t)(m0 + r0) * K + k0 + c * 16];
        arg[0] = *reinterpret_cast<const half8*>(ap);
        arg[1] = *reinterpret_cast<const half8*>(ap + 8);
        const _Float16* wp = &W[(size_t)(n0 + r0) * K + k0 + c * 16];
        brg[0] = *reinterpret_cast<const half8*>(wp);
        brg[1] = *reinterpret_cast<const half8*>(wp + 8);
    };
    auto WRITET = [&]() {
        *ldsq<16>(As, r0, 2 * c)     = arg[0];
        *ldsq<16>(As, r0, 2 * c + 1) = arg[1];
        *ldsq<16>(Bs, r0, 2 * c)     = brg[0];
        *ldsq<16>(Bs, r0, 2 * c + 1) = brg[1];
    };
    auto COMPUTET = [&]() {
        #pragma unroll
        for (int kk = 0; kk < 4; ++kk) {
            const int ch = kk * 4 + (lane >> 4);
            half8 af[2], bf;
            af[0] = *ldsq<16>(As, wr * 32 + (lane & 15), ch);
            af[1] = *ldsq<16>(As, wr * 32 + 16 + (lane & 15), ch);
            bf    = *ldsq<16>(Bs, wc * 16 + (lane & 15), ch);
            acc[0] = __builtin_amdgcn_mfma_f32_16x16x32_f16(bf, af[0], acc[0], 0, 0, 0);
            acc[1] = __builtin_amdgcn_mfma_f32_16x16x32_f16(bf, af[1], acc[1], 0, 0, 0);
        }
    };

    constexpr int nt = K / 128;    // 16
    LOADT(0); WRITET(); __syncthreads();
    for (int t = 0; t < nt - 1; ++t) {
        LOADT((t + 1) * 128);
        COMPUTET();
        __syncthreads();
        WRITET();
        __syncthreads();
    }
    COMPUTET();

    #pragma unroll
    for (int mi = 0; mi < 2; ++mi) {
        const int row  = m0 + wr * 32 + mi * 16 + (lane & 15);
        const int col0 = n0 + wc * 16 + (lane >> 4) * 4;
        const float4 bv = *reinterpret_cast<const float4*>(&bias[col0]);
        float4 o;
        o.x = eluf(acc[mi][0] + bv.x);
        o.y = eluf(acc[mi][1] + bv.y);
        o.z = eluf(acc[mi][2] + bv.z);
        o.w = eluf(acc[mi][3] + bv.w);
        *reinterpret_cast<float4*>(&Cout[(size_t)row * N + col0]) = o;
    }
}

// ---------------------------------------------------------------------------
extern "C" void kernel_launch(void* const* d_in, const int* in_sizes, int n_in,
                              void* d_out, int out_size, void* d_ws, size_t ws_size,
                              hipStream_t stream) {
    const float* x     = (const float*)d_in[0];
    const float* boxes = (const float*)d_in[1];
    const float* scale = (const float*)d_in[2];
    const float* w1    = (const float*)d_in[3];
    const float* b1    = (const float*)d_in[4];
    const float* w2    = (const float*)d_in[5];
    const float* b2    = (const float*)d_in[6];
    const float* wl    = (const float*)d_in[7];
    const float* bl    = (const float*)d_in[8];
    float* out = (float*)d_out;

    // workspace layout (fp16 halves)
    _Float16* z   = (_Float16*)d_ws;                    // 32768 x 256
    _Float16* h2  = z   + (size_t)MPIX * C1D;           //   512 x 2048
    _Float16* w1h = h2  + (size_t)R_ROI * OUTD;         //   256 x 1024
    _Float16* w2h = w1h + (size_t)C1D * C_INK;          //   128 x 256
    _Float16* wlh = w2h + (size_t)C2D * C1D;            //  2048 x 2048

    // 0) w1 -> fp16 (conv reads w1h from its first tile)
    cvt_w1<<<dim3(64), dim3(256), 0, stream>>>(w1, w1h);

    // 1) z = x @ w1^T (channels-last fp16); side-blocks convert w2/wl
    conv1x1_f16<<<dim3(NSIDE + MPIX / 64), dim3(512), 0, stream>>>(
        x, w1h, w2, wl, w2h, wlh, z);

    // 2) h2 = elu( elu(roi_align(z)+b1) @ w2^T + b2 )  -- fused, one block/ROI
    roi_gemm2_f16<<<dim3(R_ROI), dim3(512), 0, stream>>>(
        z, boxes, scale, b1, w2h, b2, h2);

    // 3) out = elu(h2 @ wl^T + bl)
    gemm_nt_out<<<dim3(256), dim3(512), 0, stream>>>(h2, wlh, bl, out);
}

// Round 10
// 77.178 us; speedup vs baseline: 1.3901x; 1.0037x over previous
//
#include <hip/hip_runtime.h>
#include <math.h>

#define C_INK   1024
#define C1D     256
#define C2D     128
#define OUTD    2048
#define R_ROI   512
#define MPIX    32768

#define NSIDE   128            // cvt side-blocks prepended to conv grid

typedef _Float16 half8 __attribute__((ext_vector_type(8)));
typedef float    f32x4 __attribute__((ext_vector_type(4)));

__device__ __forceinline__ unsigned int pack2h(float a, float b) {
    union { _Float16 h[2]; unsigned int u; } p;
    p.h[0] = (_Float16)a; p.h[1] = (_Float16)b;
    return p.u;
}
__device__ __forceinline__ float eluf(float v) { return v > 0.f ? v : expf(v) - 1.f; }

// XOR-swizzled LDS accessor: logical [row][chunk], chunk = 16B (8 halves),
// RC = chunks per row. slot = ch ^ (row&7).
template<int RC>
__device__ __forceinline__ half8* ldsq(_Float16* base, int row, int ch) {
    return reinterpret_cast<half8*>(base) + row * RC + (ch ^ (row & 7));
}

// ---------------------------------------------------------------------------
// Kernel 0: w1 fp32 -> fp16 (w1h needed by conv's B-path at kernel start)
// ---------------------------------------------------------------------------
__global__ __launch_bounds__(256) void cvt_w1(
    const float* __restrict__ w1, _Float16* __restrict__ w1h)
{
    const int i0 = (blockIdx.x * 256 + threadIdx.x) * 4;
    #pragma unroll
    for (int j = 0; j < 4; ++j) {
        const int i = (i0 + j) * 4;
        const float4 v = *reinterpret_cast<const float4*>(w1 + i);
        uint2 u; u.x = pack2h(v.x, v.y); u.y = pack2h(v.z, v.w);
        *reinterpret_cast<uint2*>(w1h + i) = u;
    }
}

// ---------------------------------------------------------------------------
// Kernel 1: conv1x1 (+ side-block conversion of w2,wl).
// z[pix][oc] = sum_k x[b][k][pix] * w1[oc][k]
// BM=64 pixels, BN=256 (full C1 -> x read once), BK=64, 512 thr = 8 waves.
// LDS: A only, double-buffered (16 KB). B (w1h fp16) straight to registers
// from L2. 2-deep prefetch, loop unrolled x2 with static reg sets.
// ---------------------------------------------------------------------------
__global__ __launch_bounds__(512, 4) void conv1x1_f16(
    const float* __restrict__ x, const _Float16* __restrict__ w1h,
    const float* __restrict__ w2, const float* __restrict__ wl,
    _Float16* __restrict__ w2h, _Float16* __restrict__ wlh,
    _Float16* __restrict__ z)
{
    const int bid = blockIdx.x;
    const int tid = threadIdx.x;

    if (bid < NSIDE) {
        // side job: convert w2 (8192 float4) then wl (1048576 float4)
        constexpr int NF4_W2 = (C2D * C1D) / 4;
        constexpr int NF4    = NF4_W2 + (OUTD * OUTD) / 4;
        for (int i = bid * 512 + tid; i < NF4; i += NSIDE * 512) {
            const float* s; _Float16* d; int e;
            if (i < NF4_W2) { s = w2; d = w2h; e = i * 4; }
            else            { s = wl; d = wlh; e = (i - NF4_W2) * 4; }
            const float4 v = *reinterpret_cast<const float4*>(s + e);
            uint2 u; u.x = pack2h(v.x, v.y); u.y = pack2h(v.z, v.w);
            *reinterpret_cast<uint2*>(d + e) = u;
        }
        return;
    }

    __shared__ __align__(16) _Float16 As[2][64 * 64];   // 2 x 8 KB

    const int lane = tid & 63;
    const int wave = tid >> 6;          // 0..7
    const int m0   = (bid - NSIDE) * 64;
    const int b    = m0 >> 12;
    const int p0   = m0 & 4095;

    const float* xbase = x + (size_t)b * C_INK * 4096 + p0 + lane;
    // B fragment base: wave's oc rows, lane's k-octet
    const _Float16* wbase = w1h + (size_t)(wave * 32 + (lane & 15)) * C_INK + (lane >> 4) * 8;

    float ar_a[8], ar_b[8];
    half8 bf_a[2][2], bf_b[2][2];
    f32x4 acc[4][2];
    #pragma unroll
    for (int i = 0; i < 4; ++i)
        #pragma unroll
        for (int j = 0; j < 2; ++j) acc[i][j] = (f32x4){0.f, 0.f, 0.f, 0.f};

    auto LOADA = [&](float (&ar)[8], int k0) {
        const float* xk = xbase + (size_t)(k0 + wave * 8) * 4096;
        #pragma unroll
        for (int j = 0; j < 8; ++j) ar[j] = xk[(size_t)j * 4096];
    };
    auto LOADB = [&](half8 (&bf)[2][2], int k0) {
        #pragma unroll
        for (int kk = 0; kk < 2; ++kk)
            #pragma unroll
            for (int ni = 0; ni < 2; ++ni)
                bf[kk][ni] = *reinterpret_cast<const half8*>(
                    wbase + (size_t)ni * 16 * C_INK + k0 + kk * 32);
    };
    auto WRITEA = [&](int buf, float (&ar)[8]) {
        union { half8 h; unsigned int u[4]; } pk;
        #pragma unroll
        for (int j = 0; j < 4; ++j) pk.u[j] = pack2h(ar[2 * j], ar[2 * j + 1]);
        *ldsq<8>(&As[buf][0], lane, wave) = pk.h;   // row = pixel, chunk = k-octet
    };
    auto COMPUTE = [&](int buf, half8 (&bf)[2][2]) {
        #pragma unroll
        for (int kk = 0; kk < 2; ++kk) {
            const int ch = kk * 4 + (lane >> 4);
            half8 af[4];
            #pragma unroll
            for (int mi = 0; mi < 4; ++mi)
                af[mi] = *ldsq<8>(&As[buf][0], mi * 16 + (lane & 15), ch);
            #pragma unroll
            for (int mi = 0; mi < 4; ++mi)
                #pragma unroll
                for (int ni = 0; ni < 2; ++ni)   // swapped: quad side = oc
                    acc[mi][ni] = __builtin_amdgcn_mfma_f32_16x16x32_f16(bf[kk][ni], af[mi], acc[mi][ni], 0, 0, 0);
        }
    };

    // prologue: tiles 0 and 1 in flight
    LOADA(ar_a, 0);   LOADB(bf_a, 0);
    LOADA(ar_b, 64);  LOADB(bf_b, 64);
    WRITEA(0, ar_a);
    __syncthreads();

    // steady state: 8 double-iterations (16 K-tiles)
    #pragma unroll
    for (int tp = 0; tp < 8; ++tp) {
        const int t = 2 * tp;
        // ---- even tile t ----
        if (tp < 7) LOADA(ar_a, (t + 2) * 64);   // issue early: used next iter
        WRITEA(1, ar_b);                         // waits only ar_b (prev iter)
        COMPUTE(0, bf_a);
        if (tp < 7) LOADB(bf_a, (t + 2) * 64);
        __syncthreads();
        // ---- odd tile t+1 ----
        if (tp < 7) {
            LOADA(ar_b, (t + 3) * 64);
            WRITEA(0, ar_a);
        }
        COMPUTE(1, bf_b);
        if (tp < 7) LOADB(bf_b, (t + 3) * 64);
        __syncthreads();
    }

    _Float16* zp = z + (size_t)m0 * C1D;
    #pragma unroll
    for (int mi = 0; mi < 4; ++mi) {
        const int pixel = mi * 16 + (lane & 15);
        #pragma unroll
        for (int ni = 0; ni < 2; ++ni) {
            const int oc0 = wave * 32 + ni * 16 + (lane >> 4) * 4;
            uint2 u;
            u.x = pack2h(acc[mi][ni][0], acc[mi][ni][1]);
            u.y = pack2h(acc[mi][ni][2], acc[mi][ni][3]);
            *reinterpret_cast<uint2*>(&zp[(size_t)pixel * C1D + oc0]) = u;
        }
    }
}

// ---------------------------------------------------------------------------
// Kernel 2: fused ROI-align gather + bias/ELU + gemm2 + bias/ELU -> h2 row.
// 512 threads, one block per ROI. w2 B-frags in registers (prefetched at
// kernel top). LDS = 16x256 H1 tile only. XCD-swizzled block->ROI map.
// ---------------------------------------------------------------------------
__global__ __launch_bounds__(512) void roi_gemm2_f16(
    const _Float16* __restrict__ z, const float* __restrict__ boxes,
    const float* __restrict__ scale_p, const float* __restrict__ b1v,
    const _Float16* __restrict__ w2h, const float* __restrict__ b2v,
    _Float16* __restrict__ h2)
{
    __shared__ __align__(16) _Float16 H1s[16 * 256];   // 8 KB, swizzled RC=32
    __shared__ int   s_off[64][4];
    __shared__ float s_w[64][4];

    const int bid  = blockIdx.x;
    const int r    = (bid & 7) * 64 + (bid >> 3);      // image i -> XCD i
    const int tid  = threadIdx.x;
    const int lane = tid & 63;
    const int wv   = tid >> 6;          // 0..7 -> output cols wv*16..wv*16+15

    // prefetch w2 B-fragments into registers (independent of gather)
    half8 bfr[8];
    {
        const _Float16* wp = w2h + (size_t)(wv * 16 + (lane & 15)) * C1D + (lane >> 4) * 8;
        #pragma unroll
        for (int ks = 0; ks < 8; ++ks)
            bfr[ks] = *reinterpret_cast<const half8*>(wp + ks * 32);
    }

    if (tid < 64) {
        const float sc = scale_p[0];
        const float x1 = boxes[r * 4 + 0] * sc, y1 = boxes[r * 4 + 1] * sc;
        const float x2 = boxes[r * 4 + 2] * sc, y2 = boxes[r * 4 + 3] * sc;
        const float rw = fmaxf(x2 - x1, 1.f), rh = fmaxf(y2 - y1, 1.f);
        const int jy = tid >> 3, jx = tid & 7;

        float offy = (float)(jy >> 1) + (float)(jy & 1) * 0.5f + 0.25f;
        float cy = y1 + offy * rh * 0.25f;
        const bool vy = (cy >= -1.f) && (cy <= 64.f);
        cy = fminf(fmaxf(cy, 0.f), 63.f);
        int ylo = (int)cy; if (ylo > 63) ylo = 63;
        int yhi = ylo + 1; if (yhi > 63) yhi = 63;
        const float ly = cy - (float)ylo, hy = 1.f - ly;

        float offx = (float)(jx >> 1) + (float)(jx & 1) * 0.5f + 0.25f;
        float cx = x1 + offx * rw * 0.25f;
        const bool vx = (cx >= -1.f) && (cx <= 64.f);
        cx = fminf(fmaxf(cx, 0.f), 63.f);
        int xlo = (int)cx; if (xlo > 63) xlo = 63;
        int xhi = xlo + 1; if (xhi > 63) xhi = 63;
        const float lx = cx - (float)xlo, hx = 1.f - lx;

        const float wm = (vy && vx) ? 0.25f : 0.f;     // fold 2x2 mean
        s_w[tid][0] = hy * hx * wm;
        s_w[tid][1] = hy * lx * wm;
        s_w[tid][2] = ly * hx * wm;
        s_w[tid][3] = ly * lx * wm;
        s_off[tid][0] = (ylo * 64 + xlo) * C1D;
        s_off[tid][1] = (ylo * 64 + xhi) * C1D;
        s_off[tid][2] = (yhi * 64 + xlo) * C1D;
        s_off[tid][3] = (yhi * 64 + xhi) * C1D;
    }
    __syncthreads();

    // gather: thread = (channel-octet ch8 = tid&31, cell = tid>>5)
    {
        const int ch8  = tid & 31;
        const int cell = tid >> 5;
        const _Float16* zb = z + (size_t)(r >> 6) * 4096 * C1D + ch8 * 8;

        float accv[8];
        #pragma unroll
        for (int e = 0; e < 8; ++e) accv[e] = 0.f;

        const int py = cell >> 2, px = cell & 3;
        #pragma unroll
        for (int u = 0; u < 4; ++u) {
            const int s = (py * 2 + (u >> 1)) * 8 + px * 2 + (u & 1);
            #pragma unroll
            for (int k = 0; k < 4; ++k) {
                const half8 v = *reinterpret_cast<const half8*>(zb + s_off[s][k]);
                const float w = s_w[s][k];
                #pragma unroll
                for (int e = 0; e < 8; ++e) accv[e] += (float)v[e] * w;
            }
        }

        const float4 b0 = *reinterpret_cast<const float4*>(&b1v[ch8 * 8]);
        const float4 b4 = *reinterpret_cast<const float4*>(&b1v[ch8 * 8 + 4]);
        half8 o;
        o[0] = (_Float16)eluf(accv[0] + b0.x); o[1] = (_Float16)eluf(accv[1] + b0.y);
        o[2] = (_Float16)eluf(accv[2] + b0.z); o[3] = (_Float16)eluf(accv[3] + b0.w);
        o[4] = (_Float16)eluf(accv[4] + b4.x); o[5] = (_Float16)eluf(accv[5] + b4.y);
        o[6] = (_Float16)eluf(accv[6] + b4.z); o[7] = (_Float16)eluf(accv[7] + b4.w);
        *ldsq<32>(H1s, cell, ch8) = o;
    }
    __syncthreads();

    // MFMA: wave wv computes C[16 cells x 16 cols], K=256
    f32x4 oa = (f32x4){0.f, 0.f, 0.f, 0.f};
    #pragma unroll
    for (int ks = 0; ks < 8; ++ks) {
        const int ch = ks * 4 + (lane >> 4);
        const half8 af = *ldsq<32>(H1s, lane & 15, ch);
        oa = __builtin_amdgcn_mfma_f32_16x16x32_f16(af, bfr[ks], oa, 0, 0, 0);
    }

    // epilogue: D cell = (lane>>4)*4+j (consecutive), col o = lane&15
    {
        const int o  = wv * 16 + (lane & 15);
        const int p0 = (lane >> 4) * 4;
        const float bv = b2v[o];
        uint2 u;
        u.x = pack2h(eluf(oa[0] + bv), eluf(oa[1] + bv));
        u.y = pack2h(eluf(oa[2] + bv), eluf(oa[3] + bv));
        *reinterpret_cast<uint2*>(&h2[(size_t)r * 2048 + o * 16 + p0]) = u;
    }
}

// ---------------------------------------------------------------------------
// Kernel 3: NT GEMM out = elu(h2 @ wl^T + bl), fp32 out.
// BM=64, BN=64, BK=128, 512 threads (8 waves 2x4, wave = 32m x 16n).
// Grid 256 flat: n-slice = bid&31 -> m-blocks of a wl slice share an XCD.
// ---------------------------------------------------------------------------
__global__ __launch_bounds__(512) void gemm_nt_out(
    const _Float16* __restrict__ A, const _Float16* __restrict__ W,
    const float* __restrict__ bias, float* __restrict__ Cout)
{
    constexpr int K = OUTD, N = OUTD;
    __shared__ __align__(16) _Float16 As[64 * 128];    // 16 KB
    __shared__ __align__(16) _Float16 Bs[64 * 128];    // 16 KB

    const int bid  = blockIdx.x;                 // 0..255
    const int m0   = (bid >> 5) * 64;
    const int n0   = (bid & 31) * 64;

    const int tid  = threadIdx.x;
    const int lane = tid & 63;
    const int wave = tid >> 6;
    const int wr   = wave >> 2, wc = wave & 3;   // wave = 32m x 16n
    const int c    = tid & 7;                    // chunk pair base
    const int r0   = tid >> 3;                   // 0..63

    half8 arg[2], brg[2];
    f32x4 acc[2];
    acc[0] = (f32x4){0.f, 0.f, 0.f, 0.f};
    acc[1] = (f32x4){0.f, 0.f, 0.f, 0.f};

    auto LOADT = [&](int k0) {
        const _Float16* ap = &A[(size_t)(m0 + r0) * K + k0 + c * 16];
        arg[0] = *reinterpret_cast<const half8*>(ap);
        arg[1] = *reinterpret_cast<const half8*>(ap + 8);
        const _Float16* wp = &W[(size_t)(n0 + r0) * K + k0 + c * 16];
        brg[0] = *reinterpret_cast<const half8*>(wp);
        brg[1] = *reinterpret_cast<const half8*>(wp + 8);
    };
    auto WRITET = [&]() {
        *ldsq<16>(As, r0, 2 * c)     = arg[0];
        *ldsq<16>(As, r0, 2 * c + 1) = arg[1];
        *ldsq<16>(Bs, r0, 2 * c)     = brg[0];
        *ldsq<16>(Bs, r0, 2 * c + 1) = brg[1];
    };
    auto COMPUTET = [&]() {
        #pragma unroll
        for (int kk = 0; kk < 4; ++kk) {
            const int ch = kk * 4 + (lane >> 4);
            half8 af[2], bf;
            af[0] = *ldsq<16>(As, wr * 32 + (lane & 15), ch);
            af[1] = *ldsq<16>(As, wr * 32 + 16 + (lane & 15), ch);
            bf    = *ldsq<16>(Bs, wc * 16 + (lane & 15), ch);
            acc[0] = __builtin_amdgcn_mfma_f32_16x16x32_f16(bf, af[0], acc[0], 0, 0, 0);
            acc[1] = __builtin_amdgcn_mfma_f32_16x16x32_f16(bf, af[1], acc[1], 0, 0, 0);
        }
    };

    constexpr int nt = K / 128;    // 16
    LOADT(0); WRITET(); __syncthreads();
    for (int t = 0; t < nt - 1; ++t) {
        LOADT((t + 1) * 128);
        COMPUTET();
        __syncthreads();
        WRITET();
        __syncthreads();
    }
    COMPUTET();

    #pragma unroll
    for (int mi = 0; mi < 2; ++mi) {
        const int row  = m0 + wr * 32 + mi * 16 + (lane & 15);
        const int col0 = n0 + wc * 16 + (lane >> 4) * 4;
        const float4 bv = *reinterpret_cast<const float4*>(&bias[col0]);
        float4 o;
        o.x = eluf(acc[mi][0] + bv.x);
        o.y = eluf(acc[mi][1] + bv.y);
        o.z = eluf(acc[mi][2] + bv.z);
        o.w = eluf(acc[mi][3] + bv.w);
        *reinterpret_cast<float4*>(&Cout[(size_t)row * N + col0]) = o;
    }
}

// ---------------------------------------------------------------------------
extern "C" void kernel_launch(void* const* d_in, const int* in_sizes, int n_in,
                              void* d_out, int out_size, void* d_ws, size_t ws_size,
                              hipStream_t stream) {
    const float* x     = (const float*)d_in[0];
    const float* boxes = (const float*)d_in[1];
    const float* scale = (const float*)d_in[2];
    const float* w1    = (const float*)d_in[3];
    const float* b1    = (const float*)d_in[4];
    const float* w2    = (const float*)d_in[5];
    const float* b2    = (const float*)d_in[6];
    const float* wl    = (const float*)d_in[7];
    const float* bl    = (const float*)d_in[8];
    float* out = (float*)d_out;

    // workspace layout (fp16 halves)
    _Float16* z   = (_Float16*)d_ws;                    // 32768 x 256
    _Float16* h2  = z   + (size_t)MPIX * C1D;           //   512 x 2048
    _Float16* w1h = h2  + (size_t)R_ROI * OUTD;         //   256 x 1024
    _Float16* w2h = w1h + (size_t)C1D * C_INK;          //   128 x 256
    _Float16* wlh = w2h + (size_t)C2D * C1D;            //  2048 x 2048

    // 0) w1 -> fp16 (conv reads w1h from its first tile)
    cvt_w1<<<dim3(64), dim3(256), 0, stream>>>(w1, w1h);

    // 1) z = x @ w1^T (channels-last fp16); side-blocks convert w2/wl
    conv1x1_f16<<<dim3(NSIDE + MPIX / 64), dim3(512), 0, stream>>>(
        x, w1h, w2, wl, w2h, wlh, z);

    // 2) h2 = elu( elu(roi_align(z)+b1) @ w2^T + b2 )  -- fused, one block/ROI
    roi_gemm2_f16<<<dim3(R_ROI), dim3(512), 0, stream>>>(
        z, boxes, scale, b1, w2h, b2, h2);

    // 3) out = elu(h2 @ wl^T + bl)
    gemm_nt_out<<<dim3(256), dim3(512), 0, stream>>>(h2, wlh, bl, out);
}